// Round 4
// baseline (14314.723 us; speedup 1.0000x reference)
//
#include <hip/hip_runtime.h>
#include <math.h>

#define BB 32
#define TT 2048
#define FF 16
#define CC 17
#define HH 64

typedef float v2f __attribute__((ext_vector_type(2)));
typedef float v4f __attribute__((ext_vector_type(4)));
typedef unsigned int v4u __attribute__((ext_vector_type(4)));
typedef _Float16 h2 __attribute__((ext_vector_type(2)));

__device__ __forceinline__ float rl(float v, int lane) {
    return __int_as_float(__builtin_amdgcn_readlane(__float_as_int(v), lane));
}
// wave-uniform value -> SGPR
__device__ __forceinline__ float uf(float v) {
    return __int_as_float(__builtin_amdgcn_readfirstlane(__float_as_int(v)));
}
// fast tanh: 1 - 2/(exp(2x)+1) via v_exp_f32 + v_rcp_f32 (~1e-6 abs err)
__device__ __forceinline__ float ftanh(float x) {
    float e = __builtin_amdgcn_exp2f(x * 2.88539008177792681472f); // exp(2x)
    return 1.0f - 2.0f * __builtin_amdgcn_rcpf(e + 1.0f);
}
// f16x2 dot with f32 accumulate
__device__ __forceinline__ float fdot2(unsigned int a, unsigned int b, float c) {
    h2 ha = __builtin_bit_cast(h2, a), hb = __builtin_bit_cast(h2, b);
#if __has_builtin(__builtin_amdgcn_fdot2)
    return __builtin_amdgcn_fdot2(ha, hb, c, false);
#else
    return fmaf((float)ha.x, (float)hb.x, fmaf((float)ha.y, (float)hb.y, c));
#endif
}
__device__ __forceinline__ unsigned int packf16(float a, float b) {
    h2 p; p.x = (_Float16)a; p.y = (_Float16)b;   // RN conversion (init-time only)
    return __builtin_bit_cast(unsigned int, p);
}

#define PIN(v) asm volatile("" : "+v"(v))

// One block per batch element. 8 waves x 64 lanes.
// Wave w owns: out column pair (c0,c1)=(2w,2w+1) as packed f16 (wo0p/wo1p, 64 regs),
//              k-slice [8w,8w+8) of the c=16 out column (w16p, 4 regs).
// Hidden-layer weights live in LDS (Wl); per-lane state fits the 128-VGPR budget
// by design (R1-R3 showed the RA refuses 256-reg allocations and spills).
__attribute__((amdgpu_waves_per_eu(2, 2)))
__launch_bounds__(512)
__global__ void ncde_main(const float* __restrict__ x,
                          const float* __restrict__ wi1, const float* __restrict__ bi1,
                          const float* __restrict__ wi2, const float* __restrict__ bi2,
                          const float* __restrict__ w_in, const float* __restrict__ b_in,
                          const float* __restrict__ w_hid, const float* __restrict__ b_hid,
                          const float* __restrict__ w_out, const float* __restrict__ b_out,
                          float* __restrict__ zT)
{
    const int b   = blockIdx.x;
    const int tid = threadIdx.x;
    const int w   = tid >> 6;
    const int l   = tid & 63;

    __shared__ float Wl[4][64][64];            // 64 KB hidden weights [layer][k][h]
    __shared__ float ph[4][8][64];             // hidden partials [layer][wave][h]
    __shared__ __align__(16) unsigned int hb16[32];  // h/256 packed f16x2
    __shared__ v2f  pgq[8][64];                // (pg, a16/256) partials per wave

    // ---- stage hidden weights into LDS (layout matches input: [k][h]) ----
    {
        float* wl = (float*)Wl;
        for (int i = tid; i < 64 * 64; i += 512)     wl[i] = w_in[i];
        for (int i = tid; i < 3 * 64 * 64; i += 512) wl[64 * 64 + i] = w_hid[i];
    }

    // biases folded into wave 0's hidden partials
    float bfold[4];
    bfold[0] = (w == 0) ? b_in[l] : 0.0f;
    bfold[1] = (w == 0) ? b_hid[0 * HH + l] : 0.0f;
    bfold[2] = (w == 0) ? b_hid[1 * HH + l] : 0.0f;
    bfold[3] = (w == 0) ? b_hid[2 * HH + l] : 0.0f;

    const int c0 = 2 * w, c1 = 2 * w + 1;
    // out-layer weights, f16-packed over k (k even/odd pairs)
    unsigned int wo0p[32], wo1p[32], w16p[4];
    #pragma unroll
    for (int j = 0; j < 32; ++j) {
        wo0p[j] = packf16(w_out[(2 * j) * (CC * HH) + l * CC + c0],
                          w_out[(2 * j + 1) * (CC * HH) + l * CC + c0]);
        wo1p[j] = packf16(w_out[(2 * j) * (CC * HH) + l * CC + c1],
                          w_out[(2 * j + 1) * (CC * HH) + l * CC + c1]);
    }
    #pragma unroll
    for (int j = 0; j < 4; ++j)
        w16p[j] = packf16(w_out[(8 * w + 2 * j) * (CC * HH) + l * CC + 16],
                          w_out[(8 * w + 2 * j + 1) * (CC * HH) + l * CC + 16]);
    float bo0  = b_out[l * CC + c0];
    float bo1  = b_out[l * CC + c1];
    float bo16 = b_out[l * CC + 16];

    #pragma unroll
    for (int j = 0; j < 32; ++j) { PIN(wo0p[j]); PIN(wo1p[j]); }
    #pragma unroll
    for (int j = 0; j < 4; ++j) PIN(w16p[j]);

    __syncthreads();   // Wl staged

    // ---- z0 = relu(xa0 @ wi1 + bi1) @ wi2 + bi2 ; xa0 = [0, x[b,0,:]] ----
    float h0 = bi1[l];
    #pragma unroll
    for (int c = 1; c < CC; ++c) {
        float xc = x[(b * TT + 0) * FF + (c - 1)];
        h0 = fmaf(xc, wi1[c * HH + l], h0);
    }
    h0 = fmaxf(h0, 0.0f);
    float z = bi2[l];
    #pragma unroll
    for (int k = 0; k < 64; ++k)
        z = fmaf(rl(h0, k), wi2[k * HH + l], z);

    if (w == 0) zT[(b * TT + 0) * HH + l] = z;

    // ---- g(zin, xd) ----
    auto G = [&](float zin, float xd0, float xd1, float xd16) -> float {
        float cur = zin;
        #pragma unroll
        for (int layer = 0; layer < 4; ++layer) {
            float wk0 = Wl[layer][8 * w + 0][l], wk1 = Wl[layer][8 * w + 1][l];
            float wk2 = Wl[layer][8 * w + 2][l], wk3 = Wl[layer][8 * w + 3][l];
            float wk4 = Wl[layer][8 * w + 4][l], wk5 = Wl[layer][8 * w + 5][l];
            float wk6 = Wl[layer][8 * w + 6][l], wk7 = Wl[layer][8 * w + 7][l];
            float a0 = bfold[layer], a1 = 0.0f;
            a0 = fmaf(rl(cur, 8 * w + 0), wk0, a0);
            a1 = fmaf(rl(cur, 8 * w + 1), wk1, a1);
            a0 = fmaf(rl(cur, 8 * w + 2), wk2, a0);
            a1 = fmaf(rl(cur, 8 * w + 3), wk3, a1);
            a0 = fmaf(rl(cur, 8 * w + 4), wk4, a0);
            a1 = fmaf(rl(cur, 8 * w + 5), wk5, a1);
            a0 = fmaf(rl(cur, 8 * w + 6), wk6, a0);
            a1 = fmaf(rl(cur, 8 * w + 7), wk7, a1);
            ph[layer][w][l] = a0 + a1;
            __syncthreads();
            float r0 = ph[layer][0][l], r1 = ph[layer][1][l];
            float r2 = ph[layer][2][l], r3 = ph[layer][3][l];
            float r4 = ph[layer][4][l], r5 = ph[layer][5][l];
            float r6 = ph[layer][6][l], r7 = ph[layer][7][l];
            cur = fmaxf(((r0 + r1) + (r2 + r3)) + ((r4 + r5) + (r6 + r7)), 0.0f);
        }
        // publish h as f16x2 pairs, scaled by 2^-8 (f16 range safety); wave 0 only
        float pm = __shfl_xor(cur, 1);
        if (w == 0 && (l & 1) == 0)
            hb16[l >> 1] = __builtin_bit_cast(unsigned int,
                __builtin_amdgcn_cvt_pkrtz(cur * 0.00390625f, pm * 0.00390625f));
        __syncthreads();

        // out layer: u[c] = 256 * sum_j dot2(h2[j], w2[c][j]) + b_out[c]
        float u0a = 0.f, u0b = 0.f, u0c = 0.f, u0d = 0.f;
        float u1a = 0.f, u1b = 0.f, u1c = 0.f, u1d = 0.f;
        #pragma unroll
        for (int j = 0; j < 8; ++j) {
            v4u q = *reinterpret_cast<const v4u*>(&hb16[4 * j]);  // uniform broadcast
            u0a = fdot2(q.x, wo0p[4 * j + 0], u0a);
            u0b = fdot2(q.y, wo0p[4 * j + 1], u0b);
            u0c = fdot2(q.z, wo0p[4 * j + 2], u0c);
            u0d = fdot2(q.w, wo0p[4 * j + 3], u0d);
            u1a = fdot2(q.x, wo1p[4 * j + 0], u1a);
            u1b = fdot2(q.y, wo1p[4 * j + 1], u1b);
            u1c = fdot2(q.z, wo1p[4 * j + 2], u1c);
            u1d = fdot2(q.w, wo1p[4 * j + 3], u1d);
        }
        float u0 = fmaf(((u0a + u0b) + (u0c + u0d)), 256.0f, bo0);
        float u1 = fmaf(((u1a + u1b) + (u1c + u1d)), 256.0f, bo1);

        // c=16 column, this wave's k-slice (scaled partial)
        v4u qc = *reinterpret_cast<const v4u*>(&hb16[4 * w]);
        float a16a = fdot2(qc.x, w16p[0], 0.0f);
        float a16b = fdot2(qc.y, w16p[1], 0.0f);
        a16a = fdot2(qc.z, w16p[2], a16a);
        a16b = fdot2(qc.w, w16p[3], a16b);

        float pg = ftanh(u0) * xd0 + ftanh(u1) * xd1;
        pgq[w][l] = (v2f){ pg, a16a + a16b };
        __syncthreads();
        v2f s0 = pgq[0][l], s1 = pgq[1][l], s2 = pgq[2][l], s3 = pgq[3][l];
        v2f s4 = pgq[4][l], s5 = pgq[5][l], s6 = pgq[6][l], s7 = pgq[7][l];
        v2f st = ((s0 + s1) + (s2 + s3)) + ((s4 + s5) + (s6 + s7));
        float u16 = fmaf(st.y, 256.0f, bo16);
        return fmaf(ftanh(u16), xd16, st.x);
    };

    // ---- time scan (x-derived scalars are wave-uniform -> SGPRs via uf) ----
    const float* xb = x + (size_t)b * TT * FF;
    const bool hasc0 = (w != 0);
    const int  f0 = 2 * w - 1;
    const int  f1 = 2 * w;
    float xp0  = hasc0 ? uf(xb[0 * FF + f0]) : 0.0f;
    float xp1  = uf(xb[0 * FF + f1]);
    float xp16 = uf(xb[0 * FF + 15]);
    float xn0  = hasc0 ? uf(xb[1 * FF + f0]) : 0.0f;
    float xn1  = uf(xb[1 * FF + f1]);
    float xn16 = uf(xb[1 * FF + 15]);
    float dc0  = hasc0 ? (xn0 - xp0) : 1.0f;
    float dc1  = xn1 - xp1;
    float dc16 = xn16 - xp16;
    float dp0 = dc0, dp1 = dc1, dp16 = dc16;
    xp0 = xn0; xp1 = xn1; xp16 = xn16;

    #pragma unroll 1
    for (int t = 0; t < TT - 1; ++t) {
        const float f43 = 4.0f / 3.0f;
        float x20  = dp0  + f43 * (dc0  - dp0);
        float x21  = dp1  + f43 * (dc1  - dp1);
        float x216 = dp16 + f43 * (dc16 - dp16);

        int tn = (t + 2 < TT) ? (t + 2) : (TT - 1);
        float yn0  = hasc0 ? uf(xb[tn * FF + f0]) : 0.0f;
        float yn1  = uf(xb[tn * FF + f1]);
        float yn16 = uf(xb[tn * FF + 15]);

        float k1 = G(z, dp0, dp1, dp16);
        float k2 = G(z + k1 * (1.0f / 3.0f), dc0, dc1, dc16);
        float k3 = G(z + (k2 - k1 * (1.0f / 3.0f)), x20, x21, x216);
        float k4 = G(z + (k1 - k2 + k3), dc0, dc1, dc16);
        z = z + 0.125f * (k1 + 3.0f * (k2 + k3) + k4);

        if (w == 0) zT[(b * TT + (t + 1)) * HH + l] = z;

        dp0 = dc0; dp1 = dc1; dp16 = dc16;
        dc0 = hasc0 ? (yn0 - xp0) : 1.0f;
        dc1 = yn1 - xp1;
        dc16 = yn16 - xp16;
        xp0 = yn0; xp1 = yn1; xp16 = yn16;
    }
}

// out = gelu_exact(zT) @ w_proj + b_proj ; mask = 0
__global__ void ncde_proj(const float* __restrict__ zT,
                          const float* __restrict__ w_proj, const float* __restrict__ b_proj,
                          float* __restrict__ out, float* __restrict__ mask)
{
    __shared__ float gz[16][64];
    const int blk = blockIdx.x;
    const int tid = threadIdx.x;
    const int r16 = tid >> 4, f = tid & 15;
    const int row0 = blk * 16;

    #pragma unroll
    for (int i = 0; i < 4; ++i) {
        int idx = tid + i * 256;
        int r = idx >> 6, k = idx & 63;
        float zv = zT[(size_t)(row0 + r) * HH + k];
        gz[r][k] = 0.5f * zv * (1.0f + erff(zv * 0.70710678118654752f));
    }
    __syncthreads();

    float acc = b_proj[f];
    #pragma unroll
    for (int k = 0; k < 64; ++k)
        acc = fmaf(gz[r16][k], w_proj[k * FF + f], acc);
    out[(size_t)(row0 + r16) * FF + f] = acc;
    if (f == 0) mask[row0 + r16] = 0.0f;
}

extern "C" void kernel_launch(void* const* d_in, const int* in_sizes, int n_in,
                              void* d_out, int out_size, void* d_ws, size_t ws_size,
                              hipStream_t stream)
{
    (void)in_sizes; (void)n_in; (void)d_ws; (void)ws_size; (void)out_size;
    const float* x      = (const float*)d_in[0];
    const float* wi1    = (const float*)d_in[1];
    const float* bi1    = (const float*)d_in[2];
    const float* wi2    = (const float*)d_in[3];
    const float* bi2    = (const float*)d_in[4];
    const float* w_in   = (const float*)d_in[5];
    const float* b_in   = (const float*)d_in[6];
    const float* w_hid  = (const float*)d_in[7];
    const float* b_hid  = (const float*)d_in[8];
    const float* w_out  = (const float*)d_in[9];
    const float* b_out  = (const float*)d_in[10];
    const float* w_proj = (const float*)d_in[11];
    const float* b_proj = (const float*)d_in[12];

    float* zT   = (float*)d_out;                       // B*T*H
    float* outp = zT + (size_t)BB * TT * HH;           // B*T*F
    float* mask = outp + (size_t)BB * TT * FF;         // B*T

    ncde_main<<<dim3(BB), dim3(512), 0, stream>>>(
        x, wi1, bi1, wi2, bi2, w_in, b_in, w_hid, b_hid, w_out, b_out, zT);
    ncde_proj<<<dim3((BB * TT) / 16), dim3(256), 0, stream>>>(
        zT, w_proj, b_proj, outp, mask);
}